// Round 6
// baseline (205.267 us; speedup 1.0000x reference)
//
#include <hip/hip_runtime.h>
#include <hip/hip_bf16.h>

typedef __hip_bfloat16 bf16;
typedef __attribute__((ext_vector_type(4))) float f32x4;
typedef __attribute__((ext_vector_type(16))) float f32x16;
typedef __attribute__((ext_vector_type(8))) __bf16 bf16x8;
typedef __attribute__((ext_vector_type(8))) unsigned short u16x8;

#define DEVI static __device__ __forceinline__

DEVI void gload_lds16(const void* g, void* l) {
  __builtin_amdgcn_global_load_lds(
      (const __attribute__((address_space(1))) void*)g,
      (__attribute__((address_space(3))) void*)l, 16, 0, 0);
}

DEVI unsigned pkbf(float a, float b) {
  union { __hip_bfloat162 h2; unsigned u; } t;
  t.h2.x = __float2bfloat16(a);
  t.h2.y = __float2bfloat16(b);
  return t.u;
}

DEVI u16x8 cvt8(f32x4 a, f32x4 b) {
  u16x8 r;
#pragma unroll
  for (int i = 0; i < 4; ++i) { bf16 h = __float2bfloat16(a[i]); r[i] = *reinterpret_cast<unsigned short*>(&h); }
#pragma unroll
  for (int i = 0; i < 4; ++i) { bf16 h = __float2bfloat16(b[i]); r[i + 4] = *reinterpret_cast<unsigned short*>(&h); }
  return r;
}

// ---------------- merged f32 -> bf16 converter ----------------
union PK4 { bf16 h[4]; unsigned long long ll; };

DEVI unsigned long long pack4(float4 v) {
  PK4 u;
  u.h[0] = __float2bfloat16(v.x); u.h[1] = __float2bfloat16(v.y);
  u.h[2] = __float2bfloat16(v.z); u.h[3] = __float2bfloat16(v.w);
  return u.ll;
}

__global__ void cvt_all(const float* __restrict__ q, const float* __restrict__ kv,
                        const float* __restrict__ wq, const float* __restrict__ wk,
                        const float* __restrict__ wv, const float* __restrict__ wo,
                        bf16* __restrict__ oq, bf16* __restrict__ okv,
                        bf16* __restrict__ owq, bf16* __restrict__ owk,
                        bf16* __restrict__ owv, bf16* __restrict__ owo) {
  int bid = blockIdx.x;
  if (bid < 4096) {
    int i = bid * 256 + threadIdx.x;
    reinterpret_cast<unsigned long long*>(oq)[i]  = pack4(reinterpret_cast<const float4*>(q)[i]);
    reinterpret_cast<unsigned long long*>(okv)[i] = pack4(reinterpret_cast<const float4*>(kv)[i]);
  } else {
    int i = (bid - 4096) * 256 + threadIdx.x;
    reinterpret_cast<unsigned long long*>(owq)[i] = pack4(reinterpret_cast<const float4*>(wq)[i]);
    reinterpret_cast<unsigned long long*>(owk)[i] = pack4(reinterpret_cast<const float4*>(wk)[i]);
    reinterpret_cast<unsigned long long*>(owv)[i] = pack4(reinterpret_cast<const float4*>(wv)[i]);
    reinterpret_cast<unsigned long long*>(owo)[i] = pack4(reinterpret_cast<const float4*>(wo)[i]);
  }
}

// ---------------- fused QKV projection GEMM, 2-phase double-buffered ----------------
// grid (64, 12): zone = by>>2 (0:Q 1:K 2:V), bn = by&3.
// Epilogue: LDS-staged transpose -> fully coalesced 16B stores.
__global__ __launch_bounds__(256) void gemm_qkv(
    const bf16* __restrict__ qb, const bf16* __restrict__ kvb,
    const bf16* __restrict__ wqb, const bf16* __restrict__ wkb, const bf16* __restrict__ wvb,
    const float* __restrict__ bq, const float* __restrict__ bk, const float* __restrict__ bv,
    bf16* __restrict__ qp, bf16* __restrict__ kp, bf16* __restrict__ vT) {
  constexpr int K = 512;
  __shared__ __align__(16) char smem[65536];
  const int tid = threadIdx.x;
  const int wave = tid >> 6, lane = tid & 63;
  const int bm = blockIdx.x;
  const int zone = blockIdx.y >> 2, bn = blockIdx.y & 3;
  const bf16* A = zone ? kvb : qb;
  const bf16* W = (zone == 0) ? wqb : (zone == 1 ? wkb : wvb);
  const float* bias = (zone == 0) ? bq : (zone == 1 ? bk : bv);
  const int wm = (wave >> 1) * 64, wn = (wave & 1) * 64;
  const int srow8 = lane >> 3, sslot = lane & 7;

  f32x4 acc[4][4] = {};

  const bf16* ap[4];
  const bf16* wp[4];
  char* adst[4];
  char* bdst[4];
#pragma unroll
  for (int i = 0; i < 4; ++i) {
    int c = wave * 4 + i;
    int row = c * 8 + srow8;
    int gs = sslot ^ (row & 7);
    ap[i] = A + (long)(bm * 128 + row) * K + gs * 8;
    wp[i] = W + (long)(bn * 128 + row) * K + gs * 8;
    adst[i] = smem + c * 1024;
    bdst[i] = smem + 16384 + c * 1024;
  }

  int aoff[2][4], boff[2][4];
#pragma unroll
  for (int ks = 0; ks < 2; ++ks)
#pragma unroll
    for (int f = 0; f < 4; ++f) {
      int r = f * 16 + (lane & 15);
      int sw = ((ks * 4 + (lane >> 4)) ^ (r & 7)) << 4;
      aoff[ks][f] = (wm + r) * 128 + sw;
      boff[ks][f] = (wn + r) * 128 + sw;
    }

#define GSTAGE(BUF)                                                       \
  _Pragma("unroll") for (int i = 0; i < 4; ++i) {                         \
    gload_lds16(ap[i], adst[i] + (BUF) * 32768);                          \
    gload_lds16(wp[i], bdst[i] + (BUF) * 32768);                          \
    ap[i] += 64; wp[i] += 64;                                             \
  }

#define GBODY(BUF, LAST)                                                  \
  {                                                                       \
    if (!(LAST)) {                                                        \
      GSTAGE((BUF) ^ 1)                                                   \
      asm volatile("s_waitcnt vmcnt(8)" ::: "memory");                    \
    } else {                                                              \
      asm volatile("s_waitcnt vmcnt(0)" ::: "memory");                    \
    }                                                                     \
    asm volatile("s_barrier" ::: "memory");                               \
    const char* Asb = smem + (BUF) * 32768;                               \
    const char* Bsb = Asb + 16384;                                        \
    _Pragma("unroll") for (int ks = 0; ks < 2; ++ks) {                    \
      bf16x8 af[4], bfv[4];                                               \
      _Pragma("unroll") for (int f = 0; f < 4; ++f) {                     \
        af[f]  = *reinterpret_cast<const bf16x8*>(Asb + aoff[ks][f]);     \
        bfv[f] = *reinterpret_cast<const bf16x8*>(Bsb + boff[ks][f]);     \
      }                                                                   \
      _Pragma("unroll") for (int mf = 0; mf < 4; ++mf)                    \
        _Pragma("unroll") for (int nf = 0; nf < 4; ++nf)                  \
          acc[mf][nf] = __builtin_amdgcn_mfma_f32_16x16x32_bf16(          \
              af[mf], bfv[nf], acc[mf][nf], 0, 0, 0);                     \
    }                                                                     \
    asm volatile("s_barrier" ::: "memory");                               \
  }

  GSTAGE(0)
#pragma unroll 1
  for (int kt = 0; kt < 8; kt += 2) {
    GBODY(0, false)
    GBODY(1, kt + 1 == 7)
  }
#undef GSTAGE
#undef GBODY

  // ---- epilogue: acc -> LDS (f32, swizzled) -> coalesced 16B bf16x8 stores ----
  // zone<2: LDS[row][col]; zone2: LDS[col][row]. 128x128 f32 = 64KB, row stride 512B.
  // swizzle: 16B-slot xor with (i&7)<<4.
#pragma unroll
  for (int nf = 0; nf < 4; ++nf) {
    int cl = wn + nf * 16 + (lane & 15);
    float bia = bias[bn * 128 + cl];
    if (zone < 2) {
#pragma unroll
      for (int mf = 0; mf < 4; ++mf) {
#pragma unroll
        for (int j = 0; j < 4; ++j) {
          int r = wm + mf * 16 + (lane >> 4) * 4 + j;
          *reinterpret_cast<float*>(smem + r * 512 + ((cl * 4) ^ ((r & 7) << 4))) =
              acc[mf][nf][j] + bia;
        }
      }
    } else {
#pragma unroll
      for (int mf = 0; mf < 4; ++mf) {
        int r0 = wm + mf * 16 + (lane >> 4) * 4;
        f32x4 v;
#pragma unroll
        for (int j = 0; j < 4; ++j) v[j] = acc[mf][nf][j] + bia;
        *reinterpret_cast<f32x4*>(smem + cl * 512 + ((r0 * 4) ^ ((cl & 7) << 4))) = v;
      }
    }
  }
  __syncthreads();
  {
    int r = tid >> 1, half = tid & 1;  // r: tile row (zone<2) or tile col (zone2)
    if (zone < 2) {
      bf16* Ob = zone ? kp : qp;
      long gbase = (long)(bm * 128 + r) * 512 + bn * 128 + half * 64;
#pragma unroll
      for (int k = 0; k < 8; ++k) {
        int c0 = half * 64 + k * 8;
        f32x4 a  = *reinterpret_cast<const f32x4*>(smem + r * 512 + ((c0 * 4) ^ ((r & 7) << 4)));
        f32x4 b2 = *reinterpret_cast<const f32x4*>(smem + r * 512 + (((c0 + 4) * 4) ^ ((r & 7) << 4)));
        *reinterpret_cast<u16x8*>(Ob + gbase + k * 8) = cvt8(a, b2);
      }
    } else {
      int gcol = bn * 128 + r;
      int hh = gcol >> 6, d = gcol & 63;
      int b0 = bm >> 4;
      long gbase = ((long)((b0 * 8 + hh) * 64 + d)) * 2048 + (bm & 15) * 128 + half * 64;
#pragma unroll
      for (int k = 0; k < 8; ++k) {
        int r0 = half * 64 + k * 8;
        f32x4 a  = *reinterpret_cast<const f32x4*>(smem + r * 512 + ((r0 * 4) ^ ((r & 7) << 4)));
        f32x4 b2 = *reinterpret_cast<const f32x4*>(smem + r * 512 + (((r0 + 4) * 4) ^ ((r & 7) << 4)));
        *reinterpret_cast<u16x8*>(vT + gbase + k * 8) = cvt8(a, b2);
      }
    }
  }
}

// ---------------- FFN GEMM: out = resid + relu(resid @ Wo^T + bo), 2-phase ----------------
__global__ __launch_bounds__(256) void gemm_ffn(
    const bf16* __restrict__ A, const bf16* __restrict__ W,
    const float* __restrict__ bias, float* __restrict__ Of) {
  constexpr int K = 512;
  __shared__ __align__(16) char smem[49152];
  const int tid = threadIdx.x;
  const int wave = tid >> 6, lane = tid & 63;
  const int bm = blockIdx.x, bn = blockIdx.y;
  const int wm = (wave >> 1) * 32, wn = (wave & 1) * 64;
  const int srow8 = lane >> 3, sslot = lane & 7;

  f32x4 acc[2][4] = {};

  const bf16* ap[2];
  const bf16* wp[4];
  char* adst[2];
  char* bdst[4];
#pragma unroll
  for (int i = 0; i < 2; ++i) {
    int c = wave * 2 + i;
    int row = c * 8 + srow8;
    int gs = sslot ^ (row & 7);
    ap[i] = A + (long)(bm * 64 + row) * K + gs * 8;
    adst[i] = smem + c * 1024;
  }
#pragma unroll
  for (int i = 0; i < 4; ++i) {
    int c = wave * 4 + i;
    int row = c * 8 + srow8;
    int gs = sslot ^ (row & 7);
    wp[i] = W + (long)(bn * 128 + row) * K + gs * 8;
    bdst[i] = smem + 8192 + c * 1024;
  }

  int aoff[2][2], boff[2][4];
#pragma unroll
  for (int ks = 0; ks < 2; ++ks) {
#pragma unroll
    for (int f = 0; f < 2; ++f) {
      int r = f * 16 + (lane & 15);
      aoff[ks][f] = (wm + r) * 128 + (((ks * 4 + (lane >> 4)) ^ (r & 7)) << 4);
    }
#pragma unroll
    for (int f = 0; f < 4; ++f) {
      int r = f * 16 + (lane & 15);
      boff[ks][f] = (wn + r) * 128 + (((ks * 4 + (lane >> 4)) ^ (r & 7)) << 4);
    }
  }

#define FSTAGE(BUF)                                                       \
  {                                                                       \
    _Pragma("unroll") for (int i = 0; i < 2; ++i) {                       \
      gload_lds16(ap[i], adst[i] + (BUF) * 24576);                        \
      ap[i] += 64;                                                        \
    }                                                                     \
    _Pragma("unroll") for (int i = 0; i < 4; ++i) {                       \
      gload_lds16(wp[i], bdst[i] + (BUF) * 24576);                        \
      wp[i] += 64;                                                        \
    }                                                                     \
  }

#define FBODY(BUF, LAST)                                                  \
  {                                                                       \
    if (!(LAST)) {                                                        \
      FSTAGE((BUF) ^ 1)                                                   \
      asm volatile("s_waitcnt vmcnt(6)" ::: "memory");                    \
    } else {                                                              \
      asm volatile("s_waitcnt vmcnt(0)" ::: "memory");                    \
    }                                                                     \
    asm volatile("s_barrier" ::: "memory");                               \
    const char* Asb = smem + (BUF) * 24576;                               \
    const char* Bsb = Asb + 8192;                                         \
    _Pragma("unroll") for (int ks = 0; ks < 2; ++ks) {                    \
      bf16x8 af[2], bfv[4];                                               \
      _Pragma("unroll") for (int f = 0; f < 2; ++f)                       \
        af[f] = *reinterpret_cast<const bf16x8*>(Asb + aoff[ks][f]);      \
      _Pragma("unroll") for (int f = 0; f < 4; ++f)                       \
        bfv[f] = *reinterpret_cast<const bf16x8*>(Bsb + boff[ks][f]);     \
      _Pragma("unroll") for (int mf = 0; mf < 2; ++mf)                    \
        _Pragma("unroll") for (int nf = 0; nf < 4; ++nf)                  \
          acc[mf][nf] = __builtin_amdgcn_mfma_f32_16x16x32_bf16(          \
              af[mf], bfv[nf], acc[mf][nf], 0, 0, 0);                     \
    }                                                                     \
    asm volatile("s_barrier" ::: "memory");                               \
  }

  FSTAGE(0)
#pragma unroll 1
  for (int kt = 0; kt < 8; kt += 2) {
    FBODY(0, false)
    FBODY(1, kt + 1 == 7)
  }
#undef FSTAGE
#undef FBODY

  // ---- epilogue: LDS transpose -> coalesced f32x4 stores (+resid+relu) ----
#pragma unroll
  for (int nf = 0; nf < 4; ++nf) {
    int cl = wn + nf * 16 + (lane & 15);
    float bia = bias[bn * 128 + cl];
#pragma unroll
    for (int mf = 0; mf < 2; ++mf) {
#pragma unroll
      for (int j = 0; j < 4; ++j) {
        int r = wm + mf * 16 + (lane >> 4) * 4 + j;
        *reinterpret_cast<float*>(smem + r * 512 + ((cl * 4) ^ ((r & 7) << 4))) =
            acc[mf][nf][j] + bia;
      }
    }
  }
  __syncthreads();
  {
    int r = tid >> 2, q = tid & 3;
    long grow = (long)(bm * 64 + r) * 512 + bn * 128 + q * 32;
#pragma unroll
    for (int k = 0; k < 8; ++k) {
      int c0 = q * 32 + k * 4;
      f32x4 v = *reinterpret_cast<const f32x4*>(smem + r * 512 + ((c0 * 4) ^ ((r & 7) << 4)));
      union { ushort4 s; unsigned short u[4]; } rin;
      rin.s = *reinterpret_cast<const ushort4*>(A + grow + k * 4);
      f32x4 o;
#pragma unroll
      for (int i = 0; i < 4; ++i) {
        float rv = __uint_as_float((unsigned)rin.u[i] << 16);
        o[i] = rv + fmaxf(v[i], 0.f);
      }
      *reinterpret_cast<f32x4*>(Of + grow + k * 4) = o;
    }
  }
}

// ---------------- attention (R4 structure + XCD-chunked swizzle) ----------------
// grid 512 (flat), 4 waves/block, wave owns 32 q rows. KVBLK=64, dbuf K/V LDS.
// swizzle: bid -> f = (bid&7)*64 + bid>>3 so the 16 q-blocks of each (b,h)
// pair share one XCD's L2 (K+V panels = 1MB x 4 bh = 4MB L2).
__global__ __launch_bounds__(256) void attn_k(
    const bf16* __restrict__ Q, const bf16* __restrict__ Kp,
    const bf16* __restrict__ VT, bf16* __restrict__ O) {
  __shared__ __align__(16) char smem[32768];
  const int tid = threadIdx.x, wave = tid >> 6, lane = tid & 63;
  const int bid = blockIdx.x;
  const int f = (bid & 7) * 64 + (bid >> 3);
  const int bh = f >> 4, qi = f & 15;
  const int b = bh >> 3, h = bh & 7;
  const int q0 = qi * 128 + wave * 32;
  const int ql = lane & 31, hl = lane >> 5;
  const long qg = ((long)(b * 2048 + q0 + ql)) * 512 + h * 64;
  const int srow8 = lane >> 3, sslot = lane & 7;

  bf16x8 qf[4];
#pragma unroll
  for (int c = 0; c < 4; ++c)
    qf[c] = *reinterpret_cast<const bf16x8*>(Q + qg + c * 16 + hl * 8);

  bf16x8 ones;
#pragma unroll
  for (int j = 0; j < 8; ++j) ones[j] = (__bf16)1.0f;

  f32x16 oacc[2] = {};
  f32x16 lacc = {};
  float m = -INFINITY;
  const float CEXP = 0.125f * 1.44269504088896f;

  const bf16* kgp[2];
  const bf16* vgp[2];
  char* kdst[2];
  char* vdst[2];
#pragma unroll
  for (int i = 0; i < 2; ++i) {
    int c = wave * 2 + i;
    int row = c * 8 + srow8;
    int gs = sslot ^ (row & 7);
    kgp[i] = Kp + ((long)(b * 2048 + row)) * 512 + h * 64 + gs * 8;
    vgp[i] = VT + ((long)(bh * 64 + row)) * 2048 + gs * 8;
    kdst[i] = smem + c * 1024;
    vdst[i] = smem + 8192 + c * 1024;
  }

  int ofs[2][4];
#pragma unroll
  for (int s = 0; s < 2; ++s)
#pragma unroll
    for (int c = 0; c < 4; ++c) {
      int row = s * 32 + ql;
      ofs[s][c] = row * 128 + (((c * 2 + hl) ^ (row & 7)) << 4);
    }

#define ASTAGE(BUF)                                                       \
  _Pragma("unroll") for (int i = 0; i < 2; ++i) {                         \
    gload_lds16(kgp[i], kdst[i] + (BUF) * 16384);                         \
    gload_lds16(vgp[i], vdst[i] + (BUF) * 16384);                         \
    kgp[i] += 32768; vgp[i] += 64;                                        \
  }

#define ABODY(BUF, LAST)                                                  \
  {                                                                       \
    if (!(LAST)) {                                                        \
      ASTAGE((BUF) ^ 1)                                                   \
      asm volatile("s_waitcnt vmcnt(4)" ::: "memory");                    \
    } else {                                                              \
      asm volatile("s_waitcnt vmcnt(0)" ::: "memory");                    \
    }                                                                     \
    asm volatile("s_barrier" ::: "memory");                               \
    const char* Kb = smem + (BUF) * 16384;                                \
    const char* Vb = Kb + 8192;                                           \
    f32x16 sacc[2] = {};                                                  \
    __builtin_amdgcn_s_setprio(1);                                        \
    _Pragma("unroll") for (int s = 0; s < 2; ++s)                         \
      _Pragma("unroll") for (int c = 0; c < 4; ++c) {                     \
        bf16x8 kf = *reinterpret_cast<const bf16x8*>(Kb + ofs[s][c]);     \
        sacc[s] = __builtin_amdgcn_mfma_f32_32x32x16_bf16(                \
            kf, qf[c], sacc[s], 0, 0, 0);                                 \
      }                                                                   \
    __builtin_amdgcn_s_setprio(0);                                        \
    float pmax = fmaxf(sacc[0][0], sacc[0][1]);                           \
    _Pragma("unroll") for (int i = 2; i < 16; i += 2)                     \
      pmax = fmaxf(fmaxf(pmax, sacc[0][i]), sacc[0][i + 1]);              \
    _Pragma("unroll") for (int i = 0; i < 16; i += 2)                     \
      pmax = fmaxf(fmaxf(pmax, sacc[1][i]), sacc[1][i + 1]);              \
    pmax = fmaxf(pmax, __shfl_xor(pmax, 32));                             \
    if (!__all(pmax - m <= 44.3614195558365f)) {                          \
      float mn = fmaxf(m, pmax);                                          \
      float al = exp2f((m - mn) * CEXP);                                  \
      m = mn;                                                             \
      _Pragma("unroll") for (int i = 0; i < 16; ++i) {                    \
        oacc[0][i] *= al; oacc[1][i] *= al; lacc[i] *= al;                \
      }                                                                   \
    }                                                                     \
    float nmC = -m * CEXP;                                                \
    float p[32];                                                          \
    _Pragma("unroll") for (int s = 0; s < 2; ++s)                         \
      _Pragma("unroll") for (int i = 0; i < 16; ++i)                      \
        p[s * 16 + i] = exp2f(fmaf(sacc[s][i], CEXP, nmC));               \
    __builtin_amdgcn_s_setprio(1);                                        \
    _Pragma("unroll") for (int s = 0; s < 2; ++s)                         \
      _Pragma("unroll") for (int jj = 0; jj < 2; ++jj) {                  \
        int base = s * 16 + jj * 8;                                       \
        unsigned w0 = pkbf(p[base + 0], p[base + 1]);                     \
        unsigned w1 = pkbf(p[base + 2], p[base + 3]);                     \
        unsigned w2 = pkbf(p[base + 4], p[base + 5]);                     \
        unsigned w3 = pkbf(p[base + 6], p[base + 7]);                     \
        asm("v_permlane32_swap_b32 %0, %1" : "+v"(w0), "+v"(w2));         \
        asm("v_permlane32_swap_b32 %0, %1" : "+v"(w1), "+v"(w3));         \
        union { unsigned u[4]; bf16x8 v; } pf;                            \
        pf.u[0] = w0; pf.u[1] = w1; pf.u[2] = w2; pf.u[3] = w3;           \
        lacc = __builtin_amdgcn_mfma_f32_32x32x16_bf16(                   \
            ones, pf.v, lacc, 0, 0, 0);                                   \
        int j = s * 2 + jj;                                               \
        _Pragma("unroll") for (int dblk = 0; dblk < 2; ++dblk) {          \
          bf16x8 vf = *reinterpret_cast<const bf16x8*>(Vb + ofs[dblk][j]);\
          oacc[dblk] = __builtin_amdgcn_mfma_f32_32x32x16_bf16(           \
              vf, pf.v, oacc[dblk], 0, 0, 0);                             \
        }                                                                 \
      }                                                                   \
    __builtin_amdgcn_s_setprio(0);                                        \
    asm volatile("s_barrier" ::: "memory");                               \
  }

  ASTAGE(0)
#pragma unroll 1
  for (int tt = 0; tt < 16; ++tt) {
    ABODY(0, false)
    ABODY(1, tt == 15)
  }
#undef ASTAGE
#undef ABODY

  float rl = 1.0f / lacc[0];
#pragma unroll
  for (int dblk = 0; dblk < 2; ++dblk) {
#pragma unroll
    for (int g = 0; g < 4; ++g) {
      int d0 = dblk * 32 + g * 8 + hl * 4;
      const long ga = qg + d0;
      union { ushort4 s; unsigned short u[4]; } qin, ov;
      qin.s = *reinterpret_cast<const ushort4*>(Q + ga);
#pragma unroll
      for (int i = 0; i < 4; ++i) {
        float qvf = __uint_as_float((unsigned)qin.u[i] << 16);
        float r = qvf + oacc[dblk][g * 4 + i] * rl;
        bf16 hb = __float2bfloat16(r);
        ov.u[i] = *reinterpret_cast<unsigned short*>(&hb);
      }
      *reinterpret_cast<ushort4*>(O + ga) = ov.s;
    }
  }
}

// ---------------- launch ----------------
extern "C" void kernel_launch(void* const* d_in, const int* in_sizes, int n_in,
                              void* d_out, int out_size, void* d_ws, size_t ws_size,
                              hipStream_t stream) {
  const float* query = (const float*)d_in[0];
  const float* keyv  = (const float*)d_in[1];
  const float* Wq = (const float*)d_in[2];
  const float* bq = (const float*)d_in[3];
  const float* Wk = (const float*)d_in[4];
  const float* bk = (const float*)d_in[5];
  const float* Wv = (const float*)d_in[6];
  const float* bv = (const float*)d_in[7];
  const float* Wo = (const float*)d_in[8];
  const float* bo = (const float*)d_in[9];
  float* out = (float*)d_out;
  char* ws = (char*)d_ws;

  bf16* qb  = (bf16*)(ws + 0);
  bf16* kvb = (bf16*)(ws + 8388608);
  bf16* wqb = (bf16*)(ws + 16777216);
  bf16* wkb = (bf16*)(ws + 17301504);
  bf16* wvb = (bf16*)(ws + 17825792);
  bf16* wob = (bf16*)(ws + 18350080);
  bf16* qp  = (bf16*)(ws + 18874368);
  bf16* kp  = (bf16*)(ws + 27262976);
  bf16* vT  = (bf16*)(ws + 35651584);
  bf16* o1  = (bf16*)(ws + 44040192);

  cvt_all<<<4352, 256, 0, stream>>>(query, keyv, Wq, Wk, Wv, Wo,
                                    qb, kvb, wqb, wkb, wvb, wob);

  gemm_qkv<<<dim3(64, 12), 256, 0, stream>>>(qb, kvb, wqb, wkb, wvb, bq, bk, bv, qp, kp, vT);

  attn_k<<<512, 256, 0, stream>>>(qp, kp, vT, o1);

  gemm_ffn<<<dim3(128, 4), 256, 0, stream>>>(o1, wob, bo, out);
}

// Round 7
// 194.433 us; speedup vs baseline: 1.0557x; 1.0557x over previous
//
#include <hip/hip_runtime.h>
#include <hip/hip_bf16.h>

typedef __hip_bfloat16 bf16;
typedef __attribute__((ext_vector_type(4))) float f32x4;
typedef __attribute__((ext_vector_type(16))) float f32x16;
typedef __attribute__((ext_vector_type(8))) __bf16 bf16x8;

#define DEVI static __device__ __forceinline__

DEVI void gload_lds16(const void* g, void* l) {
  __builtin_amdgcn_global_load_lds(
      (const __attribute__((address_space(1))) void*)g,
      (__attribute__((address_space(3))) void*)l, 16, 0, 0);
}

DEVI unsigned pkbf(float a, float b) {
  union { __hip_bfloat162 h2; unsigned u; } t;
  t.h2.x = __float2bfloat16(a);
  t.h2.y = __float2bfloat16(b);
  return t.u;
}

// ---------------- merged f32 -> bf16 converter ----------------
union PK4 { bf16 h[4]; unsigned long long ll; };

DEVI unsigned long long pack4(float4 v) {
  PK4 u;
  u.h[0] = __float2bfloat16(v.x); u.h[1] = __float2bfloat16(v.y);
  u.h[2] = __float2bfloat16(v.z); u.h[3] = __float2bfloat16(v.w);
  return u.ll;
}

__global__ void cvt_all(const float* __restrict__ q, const float* __restrict__ kv,
                        const float* __restrict__ wq, const float* __restrict__ wk,
                        const float* __restrict__ wv, const float* __restrict__ wo,
                        bf16* __restrict__ oq, bf16* __restrict__ okv,
                        bf16* __restrict__ owq, bf16* __restrict__ owk,
                        bf16* __restrict__ owv, bf16* __restrict__ owo) {
  int bid = blockIdx.x;
  if (bid < 4096) {
    int i = bid * 256 + threadIdx.x;
    reinterpret_cast<unsigned long long*>(oq)[i]  = pack4(reinterpret_cast<const float4*>(q)[i]);
    reinterpret_cast<unsigned long long*>(okv)[i] = pack4(reinterpret_cast<const float4*>(kv)[i]);
  } else {
    int i = (bid - 4096) * 256 + threadIdx.x;
    reinterpret_cast<unsigned long long*>(owq)[i] = pack4(reinterpret_cast<const float4*>(wq)[i]);
    reinterpret_cast<unsigned long long*>(owk)[i] = pack4(reinterpret_cast<const float4*>(wk)[i]);
    reinterpret_cast<unsigned long long*>(owv)[i] = pack4(reinterpret_cast<const float4*>(wv)[i]);
    reinterpret_cast<unsigned long long*>(owo)[i] = pack4(reinterpret_cast<const float4*>(wo)[i]);
  }
}

// ---------------- QKV projection GEMM: BM=64, BN=128, BK=64, 4 waves, 2-phase ----------------
// grid 1536 1-D, XCD-chunked swizzle: wgid = (bid%8)*192 + bid/8;
// bm = wgid/12 (the 12 blocks of one bm = 4 bn x 3 zones cluster on one XCD ->
// A-panel + all weights L2-hot). LDS 2 x 24KB = 48KB -> 3 blocks/CU.
__global__ __launch_bounds__(256) void gemm_zone(
    const bf16* __restrict__ qb, const bf16* __restrict__ kvb,
    const bf16* __restrict__ wqb, const bf16* __restrict__ wkb, const bf16* __restrict__ wvb,
    const float* __restrict__ bq, const float* __restrict__ bk, const float* __restrict__ bv,
    bf16* __restrict__ qp, bf16* __restrict__ kp, bf16* __restrict__ vT) {
  constexpr int K = 512;
  __shared__ __align__(16) char smem[49152];
  const int tid = threadIdx.x;
  const int wave = tid >> 6, lane = tid & 63;
  const int bid = blockIdx.x;
  const int wgid = (bid & 7) * 192 + (bid >> 3);
  const int bm = wgid / 12;
  const int rz = wgid % 12;
  const int zone = rz >> 2, bn = rz & 3;
  const bf16* A = zone ? kvb : qb;
  const bf16* W = (zone == 0) ? wqb : (zone == 1 ? wkb : wvb);
  const float* bias = (zone == 0) ? bq : (zone == 1 ? bk : bv);
  const int wm = (wave >> 1) * 32, wn = (wave & 1) * 64;
  const int srow8 = lane >> 3, sslot = lane & 7;

  f32x4 acc[2][4] = {};

  const bf16* ap[2];
  const bf16* wp[4];
  char* adst[2];
  char* bdst[4];
#pragma unroll
  for (int i = 0; i < 2; ++i) {
    int c = wave * 2 + i;
    int row = c * 8 + srow8;
    int gs = sslot ^ (row & 7);
    ap[i] = A + (long)(bm * 64 + row) * K + gs * 8;
    adst[i] = smem + c * 1024;
  }
#pragma unroll
  for (int i = 0; i < 4; ++i) {
    int c = wave * 4 + i;
    int row = c * 8 + srow8;
    int gs = sslot ^ (row & 7);
    wp[i] = W + (long)(bn * 128 + row) * K + gs * 8;
    bdst[i] = smem + 8192 + c * 1024;
  }

  int aoff[2][2], boff[2][4];
#pragma unroll
  for (int ks = 0; ks < 2; ++ks) {
#pragma unroll
    for (int f = 0; f < 2; ++f) {
      int r = f * 16 + (lane & 15);
      aoff[ks][f] = (wm + r) * 128 + (((ks * 4 + (lane >> 4)) ^ (r & 7)) << 4);
    }
#pragma unroll
    for (int f = 0; f < 4; ++f) {
      int r = f * 16 + (lane & 15);
      boff[ks][f] = (wn + r) * 128 + (((ks * 4 + (lane >> 4)) ^ (r & 7)) << 4);
    }
  }

#define ZSTAGE(BUF)                                                       \
  {                                                                       \
    _Pragma("unroll") for (int i = 0; i < 2; ++i) {                       \
      gload_lds16(ap[i], adst[i] + (BUF) * 24576);                        \
      ap[i] += 64;                                                        \
    }                                                                     \
    _Pragma("unroll") for (int i = 0; i < 4; ++i) {                       \
      gload_lds16(wp[i], bdst[i] + (BUF) * 24576);                        \
      wp[i] += 64;                                                        \
    }                                                                     \
  }

#define ZBODY(BUF, LAST)                                                  \
  {                                                                       \
    if (!(LAST)) {                                                        \
      ZSTAGE((BUF) ^ 1)                                                   \
      asm volatile("s_waitcnt vmcnt(6)" ::: "memory");                    \
    } else {                                                              \
      asm volatile("s_waitcnt vmcnt(0)" ::: "memory");                    \
    }                                                                     \
    asm volatile("s_barrier" ::: "memory");                               \
    const char* Asb = smem + (BUF) * 24576;                               \
    const char* Bsb = Asb + 8192;                                         \
    _Pragma("unroll") for (int ks = 0; ks < 2; ++ks) {                    \
      bf16x8 af[2], bfv[4];                                               \
      _Pragma("unroll") for (int f = 0; f < 2; ++f)                       \
        af[f] = *reinterpret_cast<const bf16x8*>(Asb + aoff[ks][f]);      \
      _Pragma("unroll") for (int f = 0; f < 4; ++f)                       \
        bfv[f] = *reinterpret_cast<const bf16x8*>(Bsb + boff[ks][f]);     \
      _Pragma("unroll") for (int mf = 0; mf < 2; ++mf)                    \
        _Pragma("unroll") for (int nf = 0; nf < 4; ++nf)                  \
          acc[mf][nf] = __builtin_amdgcn_mfma_f32_16x16x32_bf16(          \
              af[mf], bfv[nf], acc[mf][nf], 0, 0, 0);                     \
    }                                                                     \
    asm volatile("s_barrier" ::: "memory");                               \
  }

  ZSTAGE(0)
#pragma unroll 1
  for (int kt = 0; kt < 8; kt += 2) {
    ZBODY(0, false)
    ZBODY(1, kt + 1 == 7)
  }
#undef ZSTAGE
#undef ZBODY

#pragma unroll
  for (int nf = 0; nf < 4; ++nf) {
    int col = bn * 128 + wn + nf * 16 + (lane & 15);
    float bia = bias[col];
#pragma unroll
    for (int mf = 0; mf < 2; ++mf) {
      int row0 = bm * 64 + wm + mf * 16 + (lane >> 4) * 4;
      if (zone < 2) {
        bf16* Ob = zone ? kp : qp;
#pragma unroll
        for (int j = 0; j < 4; ++j)
          Ob[(long)(row0 + j) * 512 + col] = __float2bfloat16(acc[mf][nf][j] + bia);
      } else {
        int b = row0 >> 11, s0 = row0 & 2047;
        int h = col >> 6, d = col & 63;
        union { ushort4 s; unsigned short u[4]; } pk;
#pragma unroll
        for (int j = 0; j < 4; ++j) {
          bf16 hv = __float2bfloat16(acc[mf][nf][j] + bia);
          pk.u[j] = *reinterpret_cast<unsigned short*>(&hv);
        }
        *reinterpret_cast<ushort4*>(vT + ((long)((b * 8 + h) * 64 + d)) * 2048 + s0) = pk.s;
      }
    }
  }
}

// ---------------- FFN GEMM: out = resid + relu(resid @ Wo^T + bo), 2-phase + XCD swizzle ----
// grid 512 1-D: wgid = (bid%8)*64 + bid/8; bm = wgid>>2, bn = wgid&3.
__global__ __launch_bounds__(256) void gemm_ffn(
    const bf16* __restrict__ A, const bf16* __restrict__ W,
    const float* __restrict__ bias, float* __restrict__ Of) {
  constexpr int K = 512;
  __shared__ __align__(16) char smem[49152];
  const int tid = threadIdx.x;
  const int wave = tid >> 6, lane = tid & 63;
  const int bid = blockIdx.x;
  const int wgid = (bid & 7) * 64 + (bid >> 3);
  const int bm = wgid >> 2, bn = wgid & 3;
  const int wm = (wave >> 1) * 32, wn = (wave & 1) * 64;
  const int srow8 = lane >> 3, sslot = lane & 7;

  f32x4 acc[2][4] = {};

  const bf16* ap[2];
  const bf16* wp[4];
  char* adst[2];
  char* bdst[4];
#pragma unroll
  for (int i = 0; i < 2; ++i) {
    int c = wave * 2 + i;
    int row = c * 8 + srow8;
    int gs = sslot ^ (row & 7);
    ap[i] = A + (long)(bm * 64 + row) * K + gs * 8;
    adst[i] = smem + c * 1024;
  }
#pragma unroll
  for (int i = 0; i < 4; ++i) {
    int c = wave * 4 + i;
    int row = c * 8 + srow8;
    int gs = sslot ^ (row & 7);
    wp[i] = W + (long)(bn * 128 + row) * K + gs * 8;
    bdst[i] = smem + 8192 + c * 1024;
  }

  int aoff[2][2], boff[2][4];
#pragma unroll
  for (int ks = 0; ks < 2; ++ks) {
#pragma unroll
    for (int f = 0; f < 2; ++f) {
      int r = f * 16 + (lane & 15);
      aoff[ks][f] = (wm + r) * 128 + (((ks * 4 + (lane >> 4)) ^ (r & 7)) << 4);
    }
#pragma unroll
    for (int f = 0; f < 4; ++f) {
      int r = f * 16 + (lane & 15);
      boff[ks][f] = (wn + r) * 128 + (((ks * 4 + (lane >> 4)) ^ (r & 7)) << 4);
    }
  }

#define FSTAGE(BUF)                                                       \
  {                                                                       \
    _Pragma("unroll") for (int i = 0; i < 2; ++i) {                       \
      gload_lds16(ap[i], adst[i] + (BUF) * 24576);                        \
      ap[i] += 64;                                                        \
    }                                                                     \
    _Pragma("unroll") for (int i = 0; i < 4; ++i) {                       \
      gload_lds16(wp[i], bdst[i] + (BUF) * 24576);                        \
      wp[i] += 64;                                                        \
    }                                                                     \
  }

#define FBODY(BUF, LAST)                                                  \
  {                                                                       \
    if (!(LAST)) {                                                        \
      FSTAGE((BUF) ^ 1)                                                   \
      asm volatile("s_waitcnt vmcnt(6)" ::: "memory");                    \
    } else {                                                              \
      asm volatile("s_waitcnt vmcnt(0)" ::: "memory");                    \
    }                                                                     \
    asm volatile("s_barrier" ::: "memory");                               \
    const char* Asb = smem + (BUF) * 24576;                               \
    const char* Bsb = Asb + 8192;                                         \
    _Pragma("unroll") for (int ks = 0; ks < 2; ++ks) {                    \
      bf16x8 af[2], bfv[4];                                               \
      _Pragma("unroll") for (int f = 0; f < 2; ++f)                       \
        af[f] = *reinterpret_cast<const bf16x8*>(Asb + aoff[ks][f]);      \
      _Pragma("unroll") for (int f = 0; f < 4; ++f)                       \
        bfv[f] = *reinterpret_cast<const bf16x8*>(Bsb + boff[ks][f]);     \
      _Pragma("unroll") for (int mf = 0; mf < 2; ++mf)                    \
        _Pragma("unroll") for (int nf = 0; nf < 4; ++nf)                  \
          acc[mf][nf] = __builtin_amdgcn_mfma_f32_16x16x32_bf16(          \
              af[mf], bfv[nf], acc[mf][nf], 0, 0, 0);                     \
    }                                                                     \
    asm volatile("s_barrier" ::: "memory");                               \
  }

  FSTAGE(0)
#pragma unroll 1
  for (int kt = 0; kt < 8; kt += 2) {
    FBODY(0, false)
    FBODY(1, kt + 1 == 7)
  }
#undef FSTAGE
#undef FBODY

#pragma unroll
  for (int nf = 0; nf < 4; ++nf) {
    int col = bn * 128 + wn + nf * 16 + (lane & 15);
    float bia = bias[col];
#pragma unroll
    for (int mf = 0; mf < 2; ++mf) {
#pragma unroll
      for (int j = 0; j < 4; ++j) {
        int row = bm * 64 + wm + mf * 16 + (lane >> 4) * 4 + j;
        float r = __bfloat162float(A[(long)row * 512 + col]);
        Of[(long)row * 512 + col] = r + fmaxf(acc[mf][nf][j] + bia, 0.f);
      }
    }
  }
}

// ---------------- attention (R4-proven: swapped QK^T, in-reg softmax, MFMA row-sum) --------
// grid (16, 32): 4 waves/block, wave owns 32 q rows. KVBLK=64, double-buffered K/V LDS.
__global__ __launch_bounds__(256) void attn_k(
    const bf16* __restrict__ Q, const bf16* __restrict__ Kp,
    const bf16* __restrict__ VT, bf16* __restrict__ O) {
  __shared__ __align__(16) char smem[32768];
  const int tid = threadIdx.x, wave = tid >> 6, lane = tid & 63;
  const int bh = blockIdx.y, b = bh >> 3, h = bh & 7;
  const int q0 = blockIdx.x * 128 + wave * 32;
  const int ql = lane & 31, hl = lane >> 5;
  const long qg = ((long)(b * 2048 + q0 + ql)) * 512 + h * 64;
  const int srow8 = lane >> 3, sslot = lane & 7;

  bf16x8 qf[4];
#pragma unroll
  for (int c = 0; c < 4; ++c)
    qf[c] = *reinterpret_cast<const bf16x8*>(Q + qg + c * 16 + hl * 8);

  bf16x8 ones;
#pragma unroll
  for (int j = 0; j < 8; ++j) ones[j] = (__bf16)1.0f;

  f32x16 oacc[2] = {};
  f32x16 lacc = {};
  float m = -INFINITY;
  const float CEXP = 0.125f * 1.44269504088896f;

  const bf16* kgp[2];
  const bf16* vgp[2];
  char* kdst[2];
  char* vdst[2];
#pragma unroll
  for (int i = 0; i < 2; ++i) {
    int c = wave * 2 + i;
    int row = c * 8 + srow8;
    int gs = sslot ^ (row & 7);
    kgp[i] = Kp + ((long)(b * 2048 + row)) * 512 + h * 64 + gs * 8;
    vgp[i] = VT + ((long)(bh * 64 + row)) * 2048 + gs * 8;
    kdst[i] = smem + c * 1024;
    vdst[i] = smem + 8192 + c * 1024;
  }

  int ofs[2][4];
#pragma unroll
  for (int s = 0; s < 2; ++s)
#pragma unroll
    for (int c = 0; c < 4; ++c) {
      int row = s * 32 + ql;
      ofs[s][c] = row * 128 + (((c * 2 + hl) ^ (row & 7)) << 4);
    }

#define ASTAGE(BUF)                                                       \
  _Pragma("unroll") for (int i = 0; i < 2; ++i) {                         \
    gload_lds16(kgp[i], kdst[i] + (BUF) * 16384);                         \
    gload_lds16(vgp[i], vdst[i] + (BUF) * 16384);                         \
    kgp[i] += 32768; vgp[i] += 64;                                        \
  }

#define ABODY(BUF, LAST)                                                  \
  {                                                                       \
    if (!(LAST)) {                                                        \
      ASTAGE((BUF) ^ 1)                                                   \
      asm volatile("s_waitcnt vmcnt(4)" ::: "memory");                    \
    } else {                                                              \
      asm volatile("s_waitcnt vmcnt(0)" ::: "memory");                    \
    }                                                                     \
    asm volatile("s_barrier" ::: "memory");                               \
    const char* Kb = smem + (BUF) * 16384;                                \
    const char* Vb = Kb + 8192;                                           \
    f32x16 sacc[2] = {};                                                  \
    __builtin_amdgcn_s_setprio(1);                                        \
    _Pragma("unroll") for (int s = 0; s < 2; ++s)                         \
      _Pragma("unroll") for (int c = 0; c < 4; ++c) {                     \
        bf16x8 kf = *reinterpret_cast<const bf16x8*>(Kb + ofs[s][c]);     \
        sacc[s] = __builtin_amdgcn_mfma_f32_32x32x16_bf16(                \
            kf, qf[c], sacc[s], 0, 0, 0);                                 \
      }                                                                   \
    __builtin_amdgcn_s_setprio(0);                                        \
    float pmax = fmaxf(sacc[0][0], sacc[0][1]);                           \
    _Pragma("unroll") for (int i = 2; i < 16; i += 2)                     \
      pmax = fmaxf(fmaxf(pmax, sacc[0][i]), sacc[0][i + 1]);              \
    _Pragma("unroll") for (int i = 0; i < 16; i += 2)                     \
      pmax = fmaxf(fmaxf(pmax, sacc[1][i]), sacc[1][i + 1]);              \
    pmax = fmaxf(pmax, __shfl_xor(pmax, 32));                             \
    if (!__all(pmax - m <= 44.3614195558365f)) {                          \
      float mn = fmaxf(m, pmax);                                          \
      float al = exp2f((m - mn) * CEXP);                                  \
      m = mn;                                                             \
      _Pragma("unroll") for (int i = 0; i < 16; ++i) {                    \
        oacc[0][i] *= al; oacc[1][i] *= al; lacc[i] *= al;                \
      }                                                                   \
    }                                                                     \
    float nmC = -m * CEXP;                                                \
    float p[32];                                                          \
    _Pragma("unroll") for (int s = 0; s < 2; ++s)                         \
      _Pragma("unroll") for (int i = 0; i < 16; ++i)                      \
        p[s * 16 + i] = exp2f(fmaf(sacc[s][i], CEXP, nmC));               \
    __builtin_amdgcn_s_setprio(1);                                        \
    _Pragma("unroll") for (int s = 0; s < 2; ++s)                         \
      _Pragma("unroll") for (int jj = 0; jj < 2; ++jj) {                  \
        int base = s * 16 + jj * 8;                                       \
        unsigned w0 = pkbf(p[base + 0], p[base + 1]);                     \
        unsigned w1 = pkbf(p[base + 2], p[base + 3]);                     \
        unsigned w2 = pkbf(p[base + 4], p[base + 5]);                     \
        unsigned w3 = pkbf(p[base + 6], p[base + 7]);                     \
        asm("v_permlane32_swap_b32 %0, %1" : "+v"(w0), "+v"(w2));         \
        asm("v_permlane32_swap_b32 %0, %1" : "+v"(w1), "+v"(w3));         \
        union { unsigned u[4]; bf16x8 v; } pf;                            \
        pf.u[0] = w0; pf.u[1] = w1; pf.u[2] = w2; pf.u[3] = w3;           \
        lacc = __builtin_amdgcn_mfma_f32_32x32x16_bf16(                   \
            ones, pf.v, lacc, 0, 0, 0);                                   \
        int j = s * 2 + jj;                                               \
        _Pragma("unroll") for (int dblk = 0; dblk < 2; ++dblk) {          \
          bf16x8 vf = *reinterpret_cast<const bf16x8*>(Vb + ofs[dblk][j]);\
          oacc[dblk] = __builtin_amdgcn_mfma_f32_32x32x16_bf16(           \
              vf, pf.v, oacc[dblk], 0, 0, 0);                             \
        }                                                                 \
      }                                                                   \
    __builtin_amdgcn_s_setprio(0);                                        \
    asm volatile("s_barrier" ::: "memory");                               \
  }

  ASTAGE(0)
#pragma unroll 1
  for (int tt = 0; tt < 16; ++tt) {
    ABODY(0, false)
    ABODY(1, tt == 15)
  }
#undef ASTAGE
#undef ABODY

  float rl = 1.0f / lacc[0];
#pragma unroll
  for (int dblk = 0; dblk < 2; ++dblk) {
#pragma unroll
    for (int g = 0; g < 4; ++g) {
      int d0 = dblk * 32 + g * 8 + hl * 4;
      const long ga = qg + d0;
      union { ushort4 s; unsigned short u[4]; } qin, ov;
      qin.s = *reinterpret_cast<const ushort4*>(Q + ga);
#pragma unroll
      for (int i = 0; i < 4; ++i) {
        float qvf = __uint_as_float((unsigned)qin.u[i] << 16);
        float r = qvf + oacc[dblk][g * 4 + i] * rl;
        bf16 hb = __float2bfloat16(r);
        ov.u[i] = *reinterpret_cast<unsigned short*>(&hb);
      }
      *reinterpret_cast<ushort4*>(O + ga) = ov.s;
    }
  }
}

// ---------------- launch ----------------
extern "C" void kernel_launch(void* const* d_in, const int* in_sizes, int n_in,
                              void* d_out, int out_size, void* d_ws, size_t ws_size,
                              hipStream_t stream) {
  const float* query = (const float*)d_in[0];
  const float* keyv  = (const float*)d_in[1];
  const float* Wq = (const float*)d_in[2];
  const float* bq = (const float*)d_in[3];
  const float* Wk = (const float*)d_in[4];
  const float* bk = (const float*)d_in[5];
  const float* Wv = (const float*)d_in[6];
  const float* bv = (const float*)d_in[7];
  const float* Wo = (const float*)d_in[8];
  const float* bo = (const float*)d_in[9];
  float* out = (float*)d_out;
  char* ws = (char*)d_ws;

  bf16* qb  = (bf16*)(ws + 0);
  bf16* kvb = (bf16*)(ws + 8388608);
  bf16* wqb = (bf16*)(ws + 16777216);
  bf16* wkb = (bf16*)(ws + 17301504);
  bf16* wvb = (bf16*)(ws + 17825792);
  bf16* wob = (bf16*)(ws + 18350080);
  bf16* qp  = (bf16*)(ws + 18874368);
  bf16* kp  = (bf16*)(ws + 27262976);
  bf16* vT  = (bf16*)(ws + 35651584);
  bf16* o1  = (bf16*)(ws + 44040192);

  cvt_all<<<4352, 256, 0, stream>>>(query, keyv, Wq, Wk, Wv, Wo,
                                    qb, kvb, wqb, wkb, wvb, wob);

  gemm_zone<<<1536, 256, 0, stream>>>(qb, kvb, wqb, wkb, wvb, bq, bk, bv, qp, kp, vT);

  attn_k<<<dim3(16, 32), 256, 0, stream>>>(qp, kp, vT, o1);

  gemm_ffn<<<512, 256, 0, stream>>>(o1, wob, bo, out);
}